// Round 16
// baseline (376.149 us; speedup 1.0000x reference)
//
#include <hip/hip_runtime.h>
#include <hip/hip_bf16.h>
#include <cstddef>

typedef unsigned short u16;
typedef __attribute__((ext_vector_type(8))) short bf16x8;
typedef __attribute__((ext_vector_type(4))) float f32x4;
typedef __attribute__((ext_vector_type(2))) float f32x2;

// ---------- bf16 helpers (manual RNE, no NaN inputs here) ----------
__device__ __forceinline__ u16 f2bf_rn(float v) {
  union { float f; unsigned int u; } x; x.f = v;
  unsigned int r = x.u + 0x7fffu + ((x.u >> 16) & 1u);
  return (u16)(r >> 16);
}

__device__ __forceinline__ f32x4 splat4(float v) { f32x4 r = {v, v, v, v}; return r; }
__device__ __forceinline__ f32x4 max4(f32x4 a, f32x4 b) {
  f32x4 r; r[0]=fmaxf(a[0],b[0]); r[1]=fmaxf(a[1],b[1]); r[2]=fmaxf(a[2],b[2]); r[3]=fmaxf(a[3],b[3]); return r;
}
__device__ __forceinline__ f32x4 relu4(f32x4 a) { return max4(a, splat4(0.f)); }

// ---------- packed fp32 FMA (VOP3P). Both lanes multiply by w.lo / w.hi ----------
// pkfma_lo: acc.{lo,hi} += x.{lo,hi} * w.lo   (op_sel_hi:[1,0,1] -> high op reads S1.lo)
// pkfma_hi: acc.{lo,hi} += x.{lo,hi} * w.hi   (op_sel:[0,1,0]    -> low  op reads S1.hi)
__device__ __forceinline__ void pkfma_lo(f32x2& a, f32x2 x, f32x2 w) {
  asm("v_pk_fma_f32 %0, %1, %2, %0 op_sel_hi:[1,0,1]" : "+v"(a) : "v"(x), "v"(w));
}
__device__ __forceinline__ void pkfma_hi(f32x2& a, f32x2 x, f32x2 w) {
  asm("v_pk_fma_f32 %0, %1, %2, %0 op_sel:[0,1,0]" : "+v"(a) : "v"(x), "v"(w));
}

// ---------- global -> LDS direct copy (16B per lane) ----------
__device__ __forceinline__ void gload16(const void* g, void* l) {
  __builtin_amdgcn_global_load_lds(
      (const __attribute__((address_space(1))) void*)g,
      (__attribute__((address_space(3))) void*)l,
      16, 0, 0);
}

// ---------------- meteo transpose: [b][l][s] -> [s][l][b] ----------------
__global__ __launch_bounds__(256) void transpose_meteo(const float* __restrict__ meteo,
                                                       float* __restrict__ mT) {
  __shared__ float tile[64][65];
  const int ls0 = blockIdx.x * 64;   // over 2370 = 237*10
  const int b0  = blockIdx.y * 64;   // over 4096
  const int tx = threadIdx.x & 63;
  const int ty = threadIdx.x >> 6;   // 0..3
#pragma unroll
  for (int r = 0; r < 64; r += 4) {
    int b = b0 + ty + r;
    int ls = ls0 + tx;
    float v = (ls < 2370) ? meteo[(size_t)b*2370 + ls] : 0.f;
    tile[ty + r][tx] = v;
  }
  __syncthreads();
#pragma unroll
  for (int r = 0; r < 64; r += 4) {
    int ls = ls0 + ty + r;
    if (ls < 2370) {
      int s2 = ls % 10, l = ls / 10;
      mT[((size_t)s2*237 + l)*4096 + b0 + tx] = tile[tx][ty + r];
    }
  }
}

// ---------------- batch-vectorized conv tower (8 samples/block, 256 threads) ----------------
// R4-proven structure; inner product via v_pk_fma_f32 (2 FMAs/instr, weight
// broadcast from LDS pair halves via op_sel -> zero splat movs).
// LDS activations padded: row stride LP=L+4, logical l at entry (c*LP+l+2)*2+sg.

#define CONVV_THREADS 256

template<int COUT, int L>
__device__ __forceinline__ void zero_pads(f32x4* __restrict__ out4, int tid) {
  constexpr int LP = L + 4;
  if (tid < COUT * 8) {
    int c = tid >> 3, q = tid & 7, sg = q & 1, pi = q >> 1;
    int p = (pi < 2) ? pi : (L + pi);   // {0,1,L+2,L+3}
    out4[(c*LP + p)*2 + sg] = splat4(0.f);
  }
}

// 5-tap packed accumulate for one (o,ci): acc(pair2) += win(pair2)[t] * w[t]
__device__ __forceinline__ void tap5_pk(f32x2 acc[2], const f32x2 winp[][2], int st,
                                        f32x2 w01, f32x2 w23, f32x2 w4x) {
  pkfma_lo(acc[0], winp[st+0][0], w01); pkfma_lo(acc[1], winp[st+0][1], w01);
  pkfma_hi(acc[0], winp[st+1][0], w01); pkfma_hi(acc[1], winp[st+1][1], w01);
  pkfma_lo(acc[0], winp[st+2][0], w23); pkfma_lo(acc[1], winp[st+2][1], w23);
  pkfma_hi(acc[0], winp[st+3][0], w23); pkfma_hi(acc[1], winp[st+3][1], w23);
  pkfma_lo(acc[0], winp[st+4][0], w4x); pkfma_lo(acc[1], winp[st+4][1], w4x);
}

__device__ __forceinline__ f32x4 join_relu(const f32x2 a[2]) {
  f32x4 v; v[0]=a[0][0]; v[1]=a[0][1]; v[2]=a[1][0]; v[3]=a[1][1];
  return relu4(v);
}

// thread-per-(l-strip, sg); o-loop inside (window regs reused across COUT)
template<int CIN, int COUT, int L, int STRIP>
__device__ __forceinline__ void conv_strip_p(const f32x4* __restrict__ in4, f32x4* __restrict__ out4,
                                             const float* __restrict__ w8, const float* __restrict__ bias,
                                             int tid) {
  constexpr int LP = L + 4;
  zero_pads<COUT, L>(out4, tid);
  const int sg = tid & 1;
  const int item = tid >> 1;
  constexpr int NI = (L + STRIP - 1) / STRIP;
  if (item < NI) {
    const int l0 = item * STRIP;
    const f32x4* ibase = in4 + l0*2 + sg;
    f32x2 acc[COUT][STRIP][2];
#pragma unroll
    for (int o = 0; o < COUT; ++o) {
      float bo = bias[o];
      f32x2 bp = {bo, bo};
#pragma unroll
      for (int st = 0; st < STRIP; ++st) { acc[o][st][0] = bp; acc[o][st][1] = bp; }
    }
#pragma unroll
    for (int ci = 0; ci < CIN; ++ci) {
      const f32x4* ip = ibase + ci*LP*2;
      f32x2 winp[STRIP + 4][2];
#pragma unroll
      for (int t = 0; t < STRIP + 4; ++t) {
        f32x4 v = ip[t*2];   // ds_read_b128, folded offsets
        winp[t][0][0] = v[0]; winp[t][0][1] = v[1];
        winp[t][1][0] = v[2]; winp[t][1][1] = v[3];
      }
#pragma unroll
      for (int o = 0; o < COUT; ++o) {
        const f32x2* wpp = (const f32x2*)(w8 + (o*CIN + ci)*8);
        f32x2 w01 = wpp[0], w23 = wpp[1], w4x = wpp[2];
#pragma unroll
        for (int st = 0; st < STRIP; ++st)
          tap5_pk(acc[o][st], winp, st, w01, w23, w4x);
      }
    }
#pragma unroll
    for (int o = 0; o < COUT; ++o)
#pragma unroll
      for (int st = 0; st < STRIP; ++st)
        if (l0 + st < L) out4[(o*LP + l0 + st + 2)*2 + sg] = join_relu(acc[o][st]);
  }
}

// thread-per-(l, sg); computes o in [O0, O0+ON)
template<int CIN, int COUT, int L, int ON>
__device__ __forceinline__ void conv_pos_p(const f32x4* __restrict__ in4, f32x4* __restrict__ out4,
                                           const float* __restrict__ w8, const float* __restrict__ bias,
                                           int l, int sg, int O0) {
  constexpr int LP = L + 4;
  f32x2 acc[ON][2];
#pragma unroll
  for (int oi = 0; oi < ON; ++oi) {
    float bo = bias[O0 + oi];
    f32x2 bp = {bo, bo};
    acc[oi][0] = bp; acc[oi][1] = bp;
  }
  const f32x4* ibase = in4 + l*2 + sg;
#pragma unroll
  for (int ci = 0; ci < CIN; ++ci) {
    const f32x4* ip = ibase + ci*LP*2;
    f32x2 winp[5][2];
#pragma unroll
    for (int t = 0; t < 5; ++t) {
      f32x4 v = ip[t*2];
      winp[t][0][0] = v[0]; winp[t][0][1] = v[1];
      winp[t][1][0] = v[2]; winp[t][1][1] = v[3];
    }
#pragma unroll
    for (int oi = 0; oi < ON; ++oi) {
      const f32x2* wpp = (const f32x2*)(w8 + ((O0 + oi)*CIN + ci)*8);
      f32x2 w01 = wpp[0], w23 = wpp[1], w4x = wpp[2];
      tap5_pk(acc[oi], winp, 0, w01, w23, w4x);
    }
  }
#pragma unroll
  for (int oi = 0; oi < ON; ++oi)
    out4[((O0 + oi)*LP + l + 2)*2 + sg] = join_relu(acc[oi]);
}

template<int C, int LIN, int LOUT>
__device__ __forceinline__ void pool_p(const f32x4* __restrict__ in4, f32x4* __restrict__ out4, int tid) {
  constexpr int LPI = LIN + 4, LPO = LOUT + 4;
  zero_pads<C, LOUT>(out4, tid);
  constexpr int ITEMS = C * LOUT * 2;
  for (int idx = tid; idx < ITEMS; idx += CONVV_THREADS) {
    int sg = idx & 1;
    int r = idx >> 1;
    int c = r / LOUT;
    int lo = r - c * LOUT;
    const f32x4* p = in4 + (c*LPI + 2*lo + 2)*2 + sg;
    f32x4 m = max4(max4(max4(p[0], p[2]), max4(p[4], p[6])), p[8]);
    out4[(c*LPO + lo + 2)*2 + sg] = m;
  }
}

// A plane layout: (4096 x 3072) u16 bf16, cols 0..2969 = feat (s*297+c*27+l),
// cols 2970..3064 = x_train, 3065..3071 zero.
__global__ __launch_bounds__(CONVV_THREADS) void conv_net_kernel(
    const float* __restrict__ mT,
    const float* __restrict__ cw1, const float* __restrict__ cb1,
    const float* __restrict__ cw2, const float* __restrict__ cb2,
    const float* __restrict__ cw3, const float* __restrict__ cb3,
    const float* __restrict__ cw4, const float* __restrict__ cb4,
    const float* __restrict__ cw5, const float* __restrict__ cb5,
    const float* __restrict__ cw6, const float* __restrict__ cb6,
    u16* __restrict__ Ahi)
{
  __shared__ f32x4 bufA[2416];   // 38.7 KB  (max stage: L2 out 5x241x2=2410)
  __shared__ f32x4 bufB[1700];   // 27.2 KB  (max stage: L4 out 7x121x2=1694)
  __shared__ float wl8[2112];    // 8.4 KB, 8-float-padded (o,ci) slots
  __shared__ float bl[42];

  const int tid = threadIdx.x;
  const int bid = blockIdx.x;
  const int s = bid % 10;
  const int b0 = (bid / 10) * 8;

  // station weights -> LDS, padded to 8 floats per (o,ci) pair (proven R4 path)
#define STAGE_W(cw, sz, off8) \
  for (int i = tid; i < (sz); i += CONVV_THREADS) { int p_ = i/5, k_ = i - p_*5; wl8[(off8) + p_*8 + k_] = cw[s*(sz) + i]; }
  STAGE_W(cw1, 15, 0)
  STAGE_W(cw2, 75, 24)
  STAGE_W(cw3, 175, 144)
  STAGE_W(cw4, 245, 424)
  STAGE_W(cw5, 315, 816)
  STAGE_W(cw6, 495, 1320)
#undef STAGE_W
  if (tid < 3)  bl[tid]      = cb1[s*3  + tid];
  if (tid < 5)  bl[3  + tid] = cb2[s*5  + tid];
  if (tid < 7)  bl[8  + tid] = cb3[s*7  + tid];
  if (tid < 7)  bl[15 + tid] = cb4[s*7  + tid];
  if (tid < 9)  bl[22 + tid] = cb5[s*9  + tid];
  if (tid < 11) bl[31 + tid] = cb6[s*11 + tid];

  // input (padded, CIN=1): bufA[(l+2)*2+sg] <- mT[s][l][b0 + 4sg .. +3]
  if (tid < 8) {
    int sg = tid & 1, pi = tid >> 1;
    int p = (pi < 2) ? pi : (237 + pi);
    bufA[p*2 + sg] = splat4(0.f);
  }
  for (int idx = tid; idx < 474; idx += CONVV_THREADS) {
    int sg = idx & 1;
    int l = idx >> 1;
    bufA[(l + 2)*2 + sg] = *reinterpret_cast<const f32x4*>(&mT[((size_t)s*237 + l)*4096 + b0 + sg*4]);
  }
  __syncthreads();

  conv_strip_p<1,3,237,2>(bufA, bufB, wl8+0,   bl+0,  tid); __syncthreads();
  conv_strip_p<3,5,237,2>(bufB, bufA, wl8+24,  bl+3,  tid); __syncthreads();
  pool_p<5,237,117>(bufA, bufB, tid);                       __syncthreads();
  // L3: 5->7 at L=117, full COUT per thread
  zero_pads<7,117>(bufA, tid);
  { const int sg = tid & 1, l = tid >> 1;
    if (l < 117) conv_pos_p<5,7,117,7>(bufB, bufA, wl8+144, bl+8, l, sg, 0); }
  __syncthreads();
  // L4: 7->7 at L=117
  zero_pads<7,117>(bufB, tid);
  { const int sg = tid & 1, l = tid >> 1;
    if (l < 117) conv_pos_p<7,7,117,7>(bufA, bufB, wl8+424, bl+15, l, sg, 0); }
  __syncthreads();
  pool_p<7,117,57>(bufB, bufA, tid);                        __syncthreads();
  // L5: 7->9 at L=57, EXACT o-partition per wave-pair (no dup)
  zero_pads<9,57>(bufB, tid);
  { const int oh = tid >> 7; const int inner = tid & 127;
    const int sg = inner & 1, l = inner >> 1;
    if (l < 57) {
      if (oh == 0) conv_pos_p<7,9,57,5>(bufA, bufB, wl8+816, bl+22, l, sg, 0);
      else         conv_pos_p<7,9,57,4>(bufA, bufB, wl8+816, bl+22, l, sg, 5);
    } }
  __syncthreads();
  // L6: 9->11 at L=57, exact o-partition 6+5
  zero_pads<11,57>(bufA, tid);
  { const int oh = tid >> 7; const int inner = tid & 127;
    const int sg = inner & 1, l = inner >> 1;
    if (l < 57) {
      if (oh == 0) conv_pos_p<9,11,57,6>(bufB, bufA, wl8+1320, bl+31, l, sg, 0);
      else         conv_pos_p<9,11,57,5>(bufB, bufA, wl8+1320, bl+31, l, sg, 6);
    } }
  __syncthreads();
  // pool3 (57 -> 27) + bf16 global write; L6 rows padded LP=61
  for (int idx = tid; idx < 594; idx += CONVV_THREADS) {
    int sg = idx & 1;
    int r = idx >> 1;
    int c = r / 27;
    int lo = r - c*27;
    const f32x4* p = bufA + (c*61 + 2*lo + 2)*2 + sg;
    f32x4 m = max4(max4(max4(p[0], p[2]), max4(p[4], p[6])), p[8]);
#pragma unroll
    for (int k = 0; k < 4; ++k) {
      size_t off = (size_t)(b0 + sg*4 + k)*3072 + s*297 + c*27 + lo;
      Ahi[off] = f2bf_rn(m[k]);
    }
  }
}

__global__ void pack_xtrain_kernel(const float* __restrict__ xt,
                                   u16* __restrict__ Ahi) {
  int b = blockIdx.x;
  int j = threadIdx.x; // 128 threads
  if (j < 102) {
    float v = (j < 95) ? xt[(size_t)b*95 + j] : 0.f;
    Ahi[(size_t)b*3072 + 2970 + j] = f2bf_rn(v);
  }
}

// ---------------- weight transpose to bf16 ----------------

__device__ __forceinline__ int perm_row(int k) {
  if (k < 2970) {
    int s = k / 297;
    int r = k - s*297;
    int c = r / 27;
    int l = r - c*27;
    return (c*27 + l)*10 + s;
  }
  return k;
}

template<bool PERM>
__global__ __launch_bounds__(256) void splitw_kernel(
    const float* __restrict__ W, int Ksrc, int Nsrc,
    u16* __restrict__ WThi, int Kp)
{
  __shared__ float tile[32][33];
  const int k0 = blockIdx.x * 32;
  const int n0 = blockIdx.y * 32;
  const int tx = threadIdx.x & 31;
  const int ty = threadIdx.x >> 5;   // 0..7

#pragma unroll
  for (int r = 0; r < 32; r += 8) {
    int k = k0 + ty + r;
    int n = n0 + tx;
    float v = 0.f;
    if (k < Ksrc && n < Nsrc) {
      int ks = PERM ? perm_row(k) : k;
      v = W[(size_t)ks * Nsrc + n];
    }
    tile[ty + r][tx] = v;
  }
  __syncthreads();
#pragma unroll
  for (int r = 0; r < 32; r += 8) {
    int n = n0 + ty + r;
    int k = k0 + tx;
    WThi[(size_t)n * Kp + k] = f2bf_rn(tile[tx][ty + r]);
  }
}

// combined bias pad: blocks 0-5 -> bp1, 6-9 -> bp2, 10 -> bp3
__global__ __launch_bounds__(256) void padbias3_kernel(
    const float* __restrict__ b1, const float* __restrict__ b2, const float* __restrict__ b3,
    float* __restrict__ bp1, float* __restrict__ bp2, float* __restrict__ bp3)
{
  int blk = blockIdx.x;
  int tid = threadIdx.x;
  if (blk < 6) {
    int i = blk*256 + tid;
    if (i < 1536) bp1[i] = (i < 1500) ? b1[i] : 0.f;
  } else if (blk < 10) {
    int i = (blk-6)*256 + tid;
    if (i < 896) bp2[i] = (i < 800) ? b2[i] : 0.f;
  } else {
    if (tid < 128) bp3[tid] = (tid < 100) ? b3[tid] : 0.f;
  }
}

// ---------------- 1-pass bf16 MFMA GEMM (R14-proven) ----------------
// C = relu(Ah @ Bh^T + bias). Tile (WR*64) x 128, BK=32, WR*128 threads.

template<int KSTEPS, int WR, bool BF16_OUT>
__global__ __launch_bounds__(WR*128, 2) void gemm_mfma(
    const u16* __restrict__ Ahi, int lda,
    const u16* __restrict__ Bhi, int ldb,
    const float* __restrict__ biasp,
    u16* __restrict__ Cb,
    float* __restrict__ Cf, int ldc)
{
  constexpr int BM = WR * 64;
  constexpr int THREADS = WR * 128;
  constexpr int NROWS = THREADS / 4;   // rows staged per gload call

  __shared__ u16 sAhi[BM*32];
  __shared__ u16 sBhi[128*32];

  const int t = threadIdx.x;

  // XCD-bijective swizzle (all grids are multiples of 8 blocks)
  const int gx = gridDim.x;
  int flat = blockIdx.y * gx + blockIdx.x;
  int nwg = gx * gridDim.y;
  int cpx = nwg >> 3;
  int id = (flat & 7) * cpx + (flat >> 3);
  int mt = id / gx;
  int nt = id - mt * gx;
  const int m0 = mt * BM;
  const int n0 = nt * 128;

  const int rowS = t >> 2;           // 0..NROWS-1
  const int kb = (t & 3) * 8;
  const u16* pAh = Ahi + (size_t)(m0 + rowS) * lda + kb;
  const u16* pBh = Bhi + (size_t)(n0 + rowS) * ldb + kb;

  const int l = t & 63;
  const int w = t >> 6;
  const int wr = w >> 1, wc = w & 1;
  const int fr = l & 15;
  const int fq = l >> 4;
  const int aoff = (wr*64 + fr)*32 + fq*8;
  const int boff = (wc*64 + fr)*32 + fq*8;

  const f32x4 vzero = {0.f, 0.f, 0.f, 0.f};
  f32x4 acc[4][4];
#pragma unroll
  for (int i = 0; i < 4; ++i)
#pragma unroll
    for (int j = 0; j < 4; ++j) acc[i][j] = vzero;

  for (int kt = 0; kt < KSTEPS; ++kt) {
    // A plane: BM rows in chunks of NROWS
#pragma unroll
    for (int r = 0; r < BM; r += NROWS) {
      gload16(pAh + (size_t)r * lda, &sAhi[(r + rowS)*32 + kb]);
    }
    // B plane: 128 rows in chunks of NROWS
#pragma unroll
    for (int r = 0; r < 128; r += NROWS) {
      gload16(pBh + (size_t)r * ldb, &sBhi[(r + rowS)*32 + kb]);
    }
    pAh += 32; pBh += 32;
    __syncthreads();

    bf16x8 ah[4], bh[4];
#pragma unroll
    for (int i = 0; i < 4; ++i) ah[i] = *(const bf16x8*)&sAhi[aoff + i*512];
#pragma unroll
    for (int j = 0; j < 4; ++j) bh[j] = *(const bf16x8*)&sBhi[boff + j*512];
#pragma unroll
    for (int i = 0; i < 4; ++i)
#pragma unroll
      for (int j = 0; j < 4; ++j)
        acc[i][j] = __builtin_amdgcn_mfma_f32_16x16x32_bf16(ah[i], bh[j], acc[i][j], 0, 0, 0);
    __syncthreads();
  }

  float bv[4];
#pragma unroll
  for (int j = 0; j < 4; ++j) bv[j] = biasp[n0 + wc*64 + j*16 + fr];
#pragma unroll
  for (int i = 0; i < 4; ++i) {
#pragma unroll
    for (int q = 0; q < 4; ++q) {
      const int m = m0 + wr*64 + i*16 + fq*4 + q;
#pragma unroll
      for (int j = 0; j < 4; ++j) {
        const int n = n0 + wc*64 + j*16 + fr;
        float v = fmaxf(acc[i][j][q] + bv[j], 0.f);
        if (BF16_OUT) {
          Cb[(size_t)m*ldc + n] = f2bf_rn(v);
        } else {
          Cf[(size_t)m*ldc + n] = v;
        }
      }
    }
  }
}

// ---------------- fused tail: h4 = relu(h3@W4+b4); out = [h4,xg]@Wc+bc ----------------

__global__ __launch_bounds__(256) void tail_kernel(const float* __restrict__ h3,
                                                   const float* __restrict__ W4,
                                                   const float* __restrict__ b4,
                                                   const float* __restrict__ xg,
                                                   const float* __restrict__ Wc,
                                                   const float* __restrict__ bc,
                                                   float* __restrict__ out) {
  __shared__ float w[2000];
  __shared__ float bb[20];
  __shared__ float wc[21];
  int tid = threadIdx.x;
  for (int i = tid; i < 2000; i += 256) w[i] = W4[i];
  if (tid < 20) bb[tid] = b4[tid];
  if (tid >= 32 && tid < 53) wc[tid - 32] = Wc[tid - 32];
  __syncthreads();
  int b = blockIdx.x*256 + tid;
  if (b < 4096) {
    const float* x = h3 + (size_t)b*128;   // h3 row stride = 128
    float res = bc[0] + xg[b]*wc[20];
#pragma unroll 4
    for (int n = 0; n < 20; ++n) {
      float acc = bb[n];
      for (int k = 0; k < 100; ++k) acc += x[k] * w[k*20+n];
      res += fmaxf(acc, 0.f) * wc[n];
    }
    out[b] = res;
  }
}

// ---------------- launch ----------------

extern "C" void kernel_launch(void* const* d_in, const int* in_sizes, int n_in,
                              void* d_out, int out_size, void* d_ws, size_t ws_size,
                              hipStream_t stream) {
  const float* x_train = (const float*)d_in[0];
  const float* meteo   = (const float*)d_in[1];
  const float* xg      = (const float*)d_in[2];
  const float* cw1 = (const float*)d_in[3];  const float* cb1 = (const float*)d_in[4];
  const float* cw2 = (const float*)d_in[5];  const float* cb2 = (const float*)d_in[6];
  const float* cw3 = (const float*)d_in[7];  const float* cb3 = (const float*)d_in[8];
  const float* cw4 = (const float*)d_in[9];  const float* cb4 = (const float*)d_in[10];
  const float* cw5 = (const float*)d_in[11]; const float* cb5 = (const float*)d_in[12];
  const float* cw6 = (const float*)d_in[13]; const float* cb6 = (const float*)d_in[14];
  const float* W1 = (const float*)d_in[15];  const float* b1 = (const float*)d_in[16];
  const float* W2 = (const float*)d_in[17];  const float* b2 = (const float*)d_in[18];
  const float* W3 = (const float*)d_in[19];  const float* b3 = (const float*)d_in[20];
  const float* W4 = (const float*)d_in[21];  const float* b4 = (const float*)d_in[22];
  const float* Wc = (const float*)d_in[23];  const float* bc = (const float*)d_in[24];
  float* out = (float*)d_out;

  char* base = (char*)d_ws;
  u16* Ahi   = (u16*)(base);                 // 4096x3072 u16 = 25165824 B
  // meteoT occupies [50331648, 89161728) during conv; region is reused afterwards.
  float* mT  = (float*)(base + 50331648);
  u16* W1Thi = (u16*)(base + 50331648);      // 1536x3072 u16 (after conv)
  u16* h1hi  = (u16*)(base + 69206016);      // 4096x1536 u16
  float* bp1 = (float*)(base + 94371840);
  float* bp2 = (float*)(base + 94377984);
  float* bp3 = (float*)(base + 94381568);
  u16* W2Thi = (u16*)(base);                 // reuses Ahi region after L1
  u16* h2hi  = (u16*)(base + 5505024);       // 4096x896 u16
  u16* W3Thi = (u16*)(base + 50331648);      // reuses W1T region after L1
  float* h3  = (float*)(base + 50790400);    // 4096x128 f32

  // meteo transpose, then conv tower (mT dies after conv; W1T/h1 reuse its space)
  hipLaunchKernelGGL(transpose_meteo, dim3(38, 64), dim3(256), 0, stream, meteo, mT);
  hipLaunchKernelGGL(conv_net_kernel, dim3(5120), dim3(CONVV_THREADS), 0, stream,
                     mT, cw1, cb1, cw2, cb2, cw3, cb3, cw4, cb4, cw5, cb5, cw6, cb6,
                     Ahi);
  hipLaunchKernelGGL(pack_xtrain_kernel, dim3(4096), dim3(128), 0, stream, x_train, Ahi);

  // GEMM prep (after conv: overwrites mT region)
  hipLaunchKernelGGL(padbias3_kernel, dim3(11), dim3(256), 0, stream, b1, b2, b3, bp1, bp2, bp3);
  hipLaunchKernelGGL((splitw_kernel<true>),  dim3(96, 48), dim3(256), 0, stream,
                     W1, 3065, 1500, W1Thi, 3072);

  // L1: 4096 x 1536 x 3072, 128x128 tile, 1-pass
  hipLaunchKernelGGL((gemm_mfma<96, 2, true>), dim3(12, 32), dim3(256), 0, stream,
                     Ahi, 3072, W1Thi, 3072, bp1,
                     h1hi, (float*)nullptr, 1536);

  // W2 split, then L2: 4096 x 896 x 1536, 1-pass
  hipLaunchKernelGGL((splitw_kernel<false>), dim3(48, 28), dim3(256), 0, stream,
                     W2, 1500, 800, W2Thi, 1536);
  hipLaunchKernelGGL((gemm_mfma<48, 2, true>), dim3(7, 32), dim3(256), 0, stream,
                     h1hi, 1536, W2Thi, 1536, bp2,
                     h2hi, (float*)nullptr, 896);

  // W3 split, then L3: 4096 x 128 x 896 (fp32 out), 64x128 tile, 1-pass
  hipLaunchKernelGGL((splitw_kernel<false>), dim3(28, 4), dim3(256), 0, stream,
                     W3, 800, 100, W3Thi, 896);
  hipLaunchKernelGGL((gemm_mfma<28, 1, false>), dim3(1, 64), dim3(128), 0, stream,
                     h2hi, 896, W3Thi, 896, bp3,
                     (u16*)nullptr, h3, 128);

  // fused mlp4 + concat + final head
  hipLaunchKernelGGL(tail_kernel, dim3(16), dim3(256), 0, stream,
                     h3, W4, b4, xg, Wc, bc, out);
}

// Round 17
// 368.022 us; speedup vs baseline: 1.0221x; 1.0221x over previous
//
#include <hip/hip_runtime.h>
#include <hip/hip_bf16.h>
#include <cstddef>

typedef unsigned short u16;
typedef __attribute__((ext_vector_type(8))) short bf16x8;
typedef __attribute__((ext_vector_type(4))) float f32x4;

// ---------- bf16 helpers (manual RNE, no NaN inputs here) ----------
__device__ __forceinline__ u16 f2bf_rn(float v) {
  union { float f; unsigned int u; } x; x.f = v;
  unsigned int r = x.u + 0x7fffu + ((x.u >> 16) & 1u);
  return (u16)(r >> 16);
}

__device__ __forceinline__ f32x4 splat4(float v) { f32x4 r = {v, v, v, v}; return r; }
__device__ __forceinline__ f32x4 max4(f32x4 a, f32x4 b) {
  f32x4 r; r[0]=fmaxf(a[0],b[0]); r[1]=fmaxf(a[1],b[1]); r[2]=fmaxf(a[2],b[2]); r[3]=fmaxf(a[3],b[3]); return r;
}
__device__ __forceinline__ f32x4 relu4(f32x4 a) { return max4(a, splat4(0.f)); }

// ---------- global -> LDS direct copy (16B per lane) ----------
__device__ __forceinline__ void gload16(const void* g, void* l) {
  __builtin_amdgcn_global_load_lds(
      (const __attribute__((address_space(1))) void*)g,
      (__attribute__((address_space(3))) void*)l,
      16, 0, 0);
}

// ---------------- meteo transpose: [b][l][s] -> [s][l][b] ----------------
__global__ __launch_bounds__(256) void transpose_meteo(const float* __restrict__ meteo,
                                                       float* __restrict__ mT) {
  __shared__ float tile[64][65];
  const int ls0 = blockIdx.x * 64;   // over 2370 = 237*10
  const int b0  = blockIdx.y * 64;   // over 4096
  const int tx = threadIdx.x & 63;
  const int ty = threadIdx.x >> 6;   // 0..3
#pragma unroll
  for (int r = 0; r < 64; r += 4) {
    int b = b0 + ty + r;
    int ls = ls0 + tx;
    float v = (ls < 2370) ? meteo[(size_t)b*2370 + ls] : 0.f;
    tile[ty + r][tx] = v;
  }
  __syncthreads();
#pragma unroll
  for (int r = 0; r < 64; r += 4) {
    int ls = ls0 + ty + r;
    if (ls < 2370) {
      int s2 = ls % 10, l = ls / 10;
      mT[((size_t)s2*237 + l)*4096 + b0 + tx] = tile[tx][ty + r];
    }
  }
}

// ---------------- batch-vectorized conv tower (8 samples/block, 256 threads) ----------------
// R4-proven structure. LDS activations padded: row stride LP=L+4, logical l at entry
// (c*LP + l + 2)*2 + sg; entries {0,1,L+2,L+3} per row are zeros.
// FMA form: one product per += statement so fp-contract emits exactly one v_fma each.

#define CONVV_THREADS 256

template<int COUT, int L>
__device__ __forceinline__ void zero_pads(f32x4* __restrict__ out4, int tid) {
  constexpr int LP = L + 4;
  if (tid < COUT * 8) {
    int c = tid >> 3, q = tid & 7, sg = q & 1, pi = q >> 1;
    int p = (pi < 2) ? pi : (L + pi);   // {0,1,L+2,L+3}
    out4[(c*LP + p)*2 + sg] = splat4(0.f);
  }
}

// thread-per-(l-strip, sg); o-loop inside (window regs reused across COUT)
template<int CIN, int COUT, int L, int STRIP>
__device__ __forceinline__ void conv_strip_p(const f32x4* __restrict__ in4, f32x4* __restrict__ out4,
                                             const float* __restrict__ w8, const float* __restrict__ bias,
                                             int tid) {
  constexpr int LP = L + 4;
  zero_pads<COUT, L>(out4, tid);
  const int sg = tid & 1;
  const int item = tid >> 1;
  constexpr int NI = (L + STRIP - 1) / STRIP;
  if (item < NI) {
    const int l0 = item * STRIP;
    const f32x4* ibase = in4 + l0*2 + sg;
    f32x4 acc[COUT][STRIP];
#pragma unroll
    for (int o = 0; o < COUT; ++o) {
      float bo = bias[o];
#pragma unroll
      for (int st = 0; st < STRIP; ++st) acc[o][st] = splat4(bo);
    }
#pragma unroll
    for (int ci = 0; ci < CIN; ++ci) {
      const f32x4* ip = ibase + ci*LP*2;
      f32x4 win[STRIP + 4];
#pragma unroll
      for (int t = 0; t < STRIP + 4; ++t) win[t] = ip[t*2];   // ds_read_b128, folded offsets
#pragma unroll
      for (int o = 0; o < COUT; ++o) {
        const float* wp = w8 + (o*CIN + ci)*8;
        float4 wv = *reinterpret_cast<const float4*>(wp);
        float w4v = wp[4];
#pragma unroll
        for (int st = 0; st < STRIP; ++st) {
          acc[o][st] += win[st]   * wv.x;
          acc[o][st] += win[st+1] * wv.y;
          acc[o][st] += win[st+2] * wv.z;
          acc[o][st] += win[st+3] * wv.w;
          acc[o][st] += win[st+4] * w4v;
        }
      }
    }
#pragma unroll
    for (int o = 0; o < COUT; ++o)
#pragma unroll
      for (int st = 0; st < STRIP; ++st)
        if (l0 + st < L) out4[(o*LP + l0 + st + 2)*2 + sg] = relu4(acc[o][st]);
  }
}

// thread-per-(l, sg); computes o in [O0, O0+ON)
template<int CIN, int COUT, int L, int ON>
__device__ __forceinline__ void conv_pos_p(const f32x4* __restrict__ in4, f32x4* __restrict__ out4,
                                           const float* __restrict__ w8, const float* __restrict__ bias,
                                           int l, int sg, int O0) {
  constexpr int LP = L + 4;
  f32x4 acc[ON];
#pragma unroll
  for (int oi = 0; oi < ON; ++oi) acc[oi] = splat4(bias[O0 + oi]);
  const f32x4* ibase = in4 + l*2 + sg;
#pragma unroll
  for (int ci = 0; ci < CIN; ++ci) {
    const f32x4* ip = ibase + ci*LP*2;
    f32x4 win[5];
#pragma unroll
    for (int t = 0; t < 5; ++t) win[t] = ip[t*2];
#pragma unroll
    for (int oi = 0; oi < ON; ++oi) {
      const float* wp = w8 + ((O0 + oi)*CIN + ci)*8;
      float4 wv = *reinterpret_cast<const float4*>(wp);
      float w4v = wp[4];
      acc[oi] += win[0] * wv.x;
      acc[oi] += win[1] * wv.y;
      acc[oi] += win[2] * wv.z;
      acc[oi] += win[3] * wv.w;
      acc[oi] += win[4] * w4v;
    }
  }
#pragma unroll
  for (int oi = 0; oi < ON; ++oi)
    out4[((O0 + oi)*LP + l + 2)*2 + sg] = relu4(acc[oi]);
}

template<int C, int LIN, int LOUT>
__device__ __forceinline__ void pool_p(const f32x4* __restrict__ in4, f32x4* __restrict__ out4, int tid) {
  constexpr int LPI = LIN + 4, LPO = LOUT + 4;
  zero_pads<C, LOUT>(out4, tid);
  constexpr int ITEMS = C * LOUT * 2;
  for (int idx = tid; idx < ITEMS; idx += CONVV_THREADS) {
    int sg = idx & 1;
    int r = idx >> 1;
    int c = r / LOUT;
    int lo = r - c * LOUT;
    const f32x4* p = in4 + (c*LPI + 2*lo + 2)*2 + sg;
    f32x4 m = max4(max4(max4(p[0], p[2]), max4(p[4], p[6])), p[8]);
    out4[(c*LPO + lo + 2)*2 + sg] = m;
  }
}

// A plane layout: (4096 x 3072) u16 bf16, cols 0..2969 = feat (s*297+c*27+l),
// cols 2970..3064 = x_train, 3065..3071 zero.
__global__ __launch_bounds__(CONVV_THREADS) void conv_net_kernel(
    const float* __restrict__ mT,
    const float* __restrict__ cw1, const float* __restrict__ cb1,
    const float* __restrict__ cw2, const float* __restrict__ cb2,
    const float* __restrict__ cw3, const float* __restrict__ cb3,
    const float* __restrict__ cw4, const float* __restrict__ cb4,
    const float* __restrict__ cw5, const float* __restrict__ cb5,
    const float* __restrict__ cw6, const float* __restrict__ cb6,
    u16* __restrict__ Ahi)
{
  __shared__ f32x4 bufA[2416];   // 38.7 KB  (max stage: L2 out 5x241x2=2410)
  __shared__ f32x4 bufB[1700];   // 27.2 KB  (max stage: L4 out 7x121x2=1694)
  __shared__ float wl8[2112];    // 8.4 KB, 8-float-padded (o,ci) slots
  __shared__ float bl[42];

  const int tid = threadIdx.x;
  const int bid = blockIdx.x;
  const int s = bid % 10;
  const int b0 = (bid / 10) * 8;

  // station weights -> LDS, padded to 8 floats per (o,ci) pair (proven R4 path)
#define STAGE_W(cw, sz, off8) \
  for (int i = tid; i < (sz); i += CONVV_THREADS) { int p_ = i/5, k_ = i - p_*5; wl8[(off8) + p_*8 + k_] = cw[s*(sz) + i]; }
  STAGE_W(cw1, 15, 0)
  STAGE_W(cw2, 75, 24)
  STAGE_W(cw3, 175, 144)
  STAGE_W(cw4, 245, 424)
  STAGE_W(cw5, 315, 816)
  STAGE_W(cw6, 495, 1320)
#undef STAGE_W
  if (tid < 3)  bl[tid]      = cb1[s*3  + tid];
  if (tid < 5)  bl[3  + tid] = cb2[s*5  + tid];
  if (tid < 7)  bl[8  + tid] = cb3[s*7  + tid];
  if (tid < 7)  bl[15 + tid] = cb4[s*7  + tid];
  if (tid < 9)  bl[22 + tid] = cb5[s*9  + tid];
  if (tid < 11) bl[31 + tid] = cb6[s*11 + tid];

  // input (padded, CIN=1): bufA[(l+2)*2+sg] <- mT[s][l][b0 + 4sg .. +3]
  if (tid < 8) {
    int sg = tid & 1, pi = tid >> 1;
    int p = (pi < 2) ? pi : (237 + pi);
    bufA[p*2 + sg] = splat4(0.f);
  }
  for (int idx = tid; idx < 474; idx += CONVV_THREADS) {
    int sg = idx & 1;
    int l = idx >> 1;
    bufA[(l + 2)*2 + sg] = *reinterpret_cast<const f32x4*>(&mT[((size_t)s*237 + l)*4096 + b0 + sg*4]);
  }
  __syncthreads();

  conv_strip_p<1,3,237,2>(bufA, bufB, wl8+0,   bl+0,  tid); __syncthreads();
  conv_strip_p<3,5,237,2>(bufB, bufA, wl8+24,  bl+3,  tid); __syncthreads();
  pool_p<5,237,117>(bufA, bufB, tid);                       __syncthreads();
  // L3: 5->7 at L=117, full COUT per thread
  zero_pads<7,117>(bufA, tid);
  { const int sg = tid & 1, l = tid >> 1;
    if (l < 117) conv_pos_p<5,7,117,7>(bufB, bufA, wl8+144, bl+8, l, sg, 0); }
  __syncthreads();
  // L4: 7->7 at L=117
  zero_pads<7,117>(bufB, tid);
  { const int sg = tid & 1, l = tid >> 1;
    if (l < 117) conv_pos_p<7,7,117,7>(bufA, bufB, wl8+424, bl+15, l, sg, 0); }
  __syncthreads();
  pool_p<7,117,57>(bufB, bufA, tid);                        __syncthreads();
  // L5: 7->9 at L=57, EXACT o-partition per wave-pair (R8-proven indexing, no dup)
  zero_pads<9,57>(bufB, tid);
  { const int oh = tid >> 7; const int inner = tid & 127;
    const int sg = inner & 1, l = inner >> 1;
    if (l < 57) {
      if (oh == 0) conv_pos_p<7,9,57,5>(bufA, bufB, wl8+816, bl+22, l, sg, 0);
      else         conv_pos_p<7,9,57,4>(bufA, bufB, wl8+816, bl+22, l, sg, 5);
    } }
  __syncthreads();
  // L6: 9->11 at L=57, exact o-partition 6+5
  zero_pads<11,57>(bufA, tid);
  { const int oh = tid >> 7; const int inner = tid & 127;
    const int sg = inner & 1, l = inner >> 1;
    if (l < 57) {
      if (oh == 0) conv_pos_p<9,11,57,6>(bufB, bufA, wl8+1320, bl+31, l, sg, 0);
      else         conv_pos_p<9,11,57,5>(bufB, bufA, wl8+1320, bl+31, l, sg, 6);
    } }
  __syncthreads();
  // pool3 (57 -> 27) + bf16 global write; L6 rows padded LP=61
  for (int idx = tid; idx < 594; idx += CONVV_THREADS) {
    int sg = idx & 1;
    int r = idx >> 1;
    int c = r / 27;
    int lo = r - c*27;
    const f32x4* p = bufA + (c*61 + 2*lo + 2)*2 + sg;
    f32x4 m = max4(max4(max4(p[0], p[2]), max4(p[4], p[6])), p[8]);
#pragma unroll
    for (int k = 0; k < 4; ++k) {
      size_t off = (size_t)(b0 + sg*4 + k)*3072 + s*297 + c*27 + lo;
      Ahi[off] = f2bf_rn(m[k]);
    }
  }
}

__global__ void pack_xtrain_kernel(const float* __restrict__ xt,
                                   u16* __restrict__ Ahi) {
  int b = blockIdx.x;
  int j = threadIdx.x; // 128 threads
  if (j < 102) {
    float v = (j < 95) ? xt[(size_t)b*95 + j] : 0.f;
    Ahi[(size_t)b*3072 + 2970 + j] = f2bf_rn(v);
  }
}

// ---------------- weight transpose to bf16 ----------------

__device__ __forceinline__ int perm_row(int k) {
  if (k < 2970) {
    int s = k / 297;
    int r = k - s*297;
    int c = r / 27;
    int l = r - c*27;
    return (c*27 + l)*10 + s;
  }
  return k;
}

template<bool PERM>
__global__ __launch_bounds__(256) void splitw_kernel(
    const float* __restrict__ W, int Ksrc, int Nsrc,
    u16* __restrict__ WThi, int Kp)
{
  __shared__ float tile[32][33];
  const int k0 = blockIdx.x * 32;
  const int n0 = blockIdx.y * 32;
  const int tx = threadIdx.x & 31;
  const int ty = threadIdx.x >> 5;   // 0..7

#pragma unroll
  for (int r = 0; r < 32; r += 8) {
    int k = k0 + ty + r;
    int n = n0 + tx;
    float v = 0.f;
    if (k < Ksrc && n < Nsrc) {
      int ks = PERM ? perm_row(k) : k;
      v = W[(size_t)ks * Nsrc + n];
    }
    tile[ty + r][tx] = v;
  }
  __syncthreads();
#pragma unroll
  for (int r = 0; r < 32; r += 8) {
    int n = n0 + ty + r;
    int k = k0 + tx;
    WThi[(size_t)n * Kp + k] = f2bf_rn(tile[tx][ty + r]);
  }
}

// combined bias pad: blocks 0-5 -> bp1, 6-9 -> bp2, 10 -> bp3
__global__ __launch_bounds__(256) void padbias3_kernel(
    const float* __restrict__ b1, const float* __restrict__ b2, const float* __restrict__ b3,
    float* __restrict__ bp1, float* __restrict__ bp2, float* __restrict__ bp3)
{
  int blk = blockIdx.x;
  int tid = threadIdx.x;
  if (blk < 6) {
    int i = blk*256 + tid;
    if (i < 1536) bp1[i] = (i < 1500) ? b1[i] : 0.f;
  } else if (blk < 10) {
    int i = (blk-6)*256 + tid;
    if (i < 896) bp2[i] = (i < 800) ? b2[i] : 0.f;
  } else {
    if (tid < 128) bp3[tid] = (tid < 100) ? b3[tid] : 0.f;
  }
}

// ---------------- 1-pass bf16 MFMA GEMM (R14-proven) ----------------
// C = relu(Ah @ Bh^T + bias). Tile (WR*64) x 128, BK=32, WR*128 threads.

template<int KSTEPS, int WR, bool BF16_OUT>
__global__ __launch_bounds__(WR*128, 2) void gemm_mfma(
    const u16* __restrict__ Ahi, int lda,
    const u16* __restrict__ Bhi, int ldb,
    const float* __restrict__ biasp,
    u16* __restrict__ Cb,
    float* __restrict__ Cf, int ldc)
{
  constexpr int BM = WR * 64;
  constexpr int THREADS = WR * 128;
  constexpr int NROWS = THREADS / 4;   // rows staged per gload call

  __shared__ u16 sAhi[BM*32];
  __shared__ u16 sBhi[128*32];

  const int t = threadIdx.x;

  // XCD-bijective swizzle (all grids are multiples of 8 blocks)
  const int gx = gridDim.x;
  int flat = blockIdx.y * gx + blockIdx.x;
  int nwg = gx * gridDim.y;
  int cpx = nwg >> 3;
  int id = (flat & 7) * cpx + (flat >> 3);
  int mt = id / gx;
  int nt = id - mt * gx;
  const int m0 = mt * BM;
  const int n0 = nt * 128;

  const int rowS = t >> 2;           // 0..NROWS-1
  const int kb = (t & 3) * 8;
  const u16* pAh = Ahi + (size_t)(m0 + rowS) * lda + kb;
  const u16* pBh = Bhi + (size_t)(n0 + rowS) * ldb + kb;

  const int l = t & 63;
  const int w = t >> 6;
  const int wr = w >> 1, wc = w & 1;
  const int fr = l & 15;
  const int fq = l >> 4;
  const int aoff = (wr*64 + fr)*32 + fq*8;
  const int boff = (wc*64 + fr)*32 + fq*8;

  const f32x4 vzero = {0.f, 0.f, 0.f, 0.f};
  f32x4 acc[4][4];
#pragma unroll
  for (int i = 0; i < 4; ++i)
#pragma unroll
    for (int j = 0; j < 4; ++j) acc[i][j] = vzero;

  for (int kt = 0; kt < KSTEPS; ++kt) {
    // A plane: BM rows in chunks of NROWS
#pragma unroll
    for (int r = 0; r < BM; r += NROWS) {
      gload16(pAh + (size_t)r * lda, &sAhi[(r + rowS)*32 + kb]);
    }
    // B plane: 128 rows in chunks of NROWS
#pragma unroll
    for (int r = 0; r < 128; r += NROWS) {
      gload16(pBh + (size_t)r * ldb, &sBhi[(r + rowS)*32 + kb]);
    }
    pAh += 32; pBh += 32;
    __syncthreads();

    bf16x8 ah[4], bh[4];
#pragma unroll
    for (int i = 0; i < 4; ++i) ah[i] = *(const bf16x8*)&sAhi[aoff + i*512];
#pragma unroll
    for (int j = 0; j < 4; ++j) bh[j] = *(const bf16x8*)&sBhi[boff + j*512];
#pragma unroll
    for (int i = 0; i < 4; ++i)
#pragma unroll
      for (int j = 0; j < 4; ++j)
        acc[i][j] = __builtin_amdgcn_mfma_f32_16x16x32_bf16(ah[i], bh[j], acc[i][j], 0, 0, 0);
    __syncthreads();
  }

  float bv[4];
#pragma unroll
  for (int j = 0; j < 4; ++j) bv[j] = biasp[n0 + wc*64 + j*16 + fr];
#pragma unroll
  for (int i = 0; i < 4; ++i) {
#pragma unroll
    for (int q = 0; q < 4; ++q) {
      const int m = m0 + wr*64 + i*16 + fq*4 + q;
#pragma unroll
      for (int j = 0; j < 4; ++j) {
        const int n = n0 + wc*64 + j*16 + fr;
        float v = fmaxf(acc[i][j][q] + bv[j], 0.f);
        if (BF16_OUT) {
          Cb[(size_t)m*ldc + n] = f2bf_rn(v);
        } else {
          Cf[(size_t)m*ldc + n] = v;
        }
      }
    }
  }
}

// ---------------- fused tail: h4 = relu(h3@W4+b4); out = [h4,xg]@Wc+bc ----------------

__global__ __launch_bounds__(256) void tail_kernel(const float* __restrict__ h3,
                                                   const float* __restrict__ W4,
                                                   const float* __restrict__ b4,
                                                   const float* __restrict__ xg,
                                                   const float* __restrict__ Wc,
                                                   const float* __restrict__ bc,
                                                   float* __restrict__ out) {
  __shared__ float w[2000];
  __shared__ float bb[20];
  __shared__ float wc[21];
  int tid = threadIdx.x;
  for (int i = tid; i < 2000; i += 256) w[i] = W4[i];
  if (tid < 20) bb[tid] = b4[tid];
  if (tid >= 32 && tid < 53) wc[tid - 32] = Wc[tid - 32];
  __syncthreads();
  int b = blockIdx.x*256 + tid;
  if (b < 4096) {
    const float* x = h3 + (size_t)b*128;   // h3 row stride = 128
    float res = bc[0] + xg[b]*wc[20];
#pragma unroll 4
    for (int n = 0; n < 20; ++n) {
      float acc = bb[n];
      for (int k = 0; k < 100; ++k) acc += x[k] * w[k*20+n];
      res += fmaxf(acc, 0.f) * wc[n];
    }
    out[b] = res;
  }
}

// ---------------- launch ----------------

extern "C" void kernel_launch(void* const* d_in, const int* in_sizes, int n_in,
                              void* d_out, int out_size, void* d_ws, size_t ws_size,
                              hipStream_t stream) {
  const float* x_train = (const float*)d_in[0];
  const float* meteo   = (const float*)d_in[1];
  const float* xg      = (const float*)d_in[2];
  const float* cw1 = (const float*)d_in[3];  const float* cb1 = (const float*)d_in[4];
  const float* cw2 = (const float*)d_in[5];  const float* cb2 = (const float*)d_in[6];
  const float* cw3 = (const float*)d_in[7];  const float* cb3 = (const float*)d_in[8];
  const float* cw4 = (const float*)d_in[9];  const float* cb4 = (const float*)d_in[10];
  const float* cw5 = (const float*)d_in[11]; const float* cb5 = (const float*)d_in[12];
  const float* cw6 = (const float*)d_in[13]; const float* cb6 = (const float*)d_in[14];
  const float* W1 = (const float*)d_in[15];  const float* b1 = (const float*)d_in[16];
  const float* W2 = (const float*)d_in[17];  const float* b2 = (const float*)d_in[18];
  const float* W3 = (const float*)d_in[19];  const float* b3 = (const float*)d_in[20];
  const float* W4 = (const float*)d_in[21];  const float* b4 = (const float*)d_in[22];
  const float* Wc = (const float*)d_in[23];  const float* bc = (const float*)d_in[24];
  float* out = (float*)d_out;

  char* base = (char*)d_ws;
  u16* Ahi   = (u16*)(base);                 // 4096x3072 u16 = 25165824 B
  // meteoT occupies [50331648, 89161728) during conv; region is reused afterwards.
  float* mT  = (float*)(base + 50331648);
  u16* W1Thi = (u16*)(base + 50331648);      // 1536x3072 u16 (after conv)
  u16* h1hi  = (u16*)(base + 69206016);      // 4096x1536 u16
  float* bp1 = (float*)(base + 94371840);
  float* bp2 = (float*)(base + 94377984);
  float* bp3 = (float*)(base + 94381568);
  u16* W2Thi = (u16*)(base);                 // reuses Ahi region after L1
  u16* h2hi  = (u16*)(base + 5505024);       // 4096x896 u16
  u16* W3Thi = (u16*)(base + 50331648);      // reuses W1T region after L1
  float* h3  = (float*)(base + 50790400);    // 4096x128 f32

  // meteo transpose, then conv tower (mT dies after conv; W1T/h1 reuse its space)
  hipLaunchKernelGGL(transpose_meteo, dim3(38, 64), dim3(256), 0, stream, meteo, mT);
  hipLaunchKernelGGL(conv_net_kernel, dim3(5120), dim3(CONVV_THREADS), 0, stream,
                     mT, cw1, cb1, cw2, cb2, cw3, cb3, cw4, cb4, cw5, cb5, cw6, cb6,
                     Ahi);
  hipLaunchKernelGGL(pack_xtrain_kernel, dim3(4096), dim3(128), 0, stream, x_train, Ahi);

  // GEMM prep (after conv: overwrites mT region)
  hipLaunchKernelGGL(padbias3_kernel, dim3(11), dim3(256), 0, stream, b1, b2, b3, bp1, bp2, bp3);
  hipLaunchKernelGGL((splitw_kernel<true>),  dim3(96, 48), dim3(256), 0, stream,
                     W1, 3065, 1500, W1Thi, 3072);

  // L1: 4096 x 1536 x 3072, 128x128 tile, 1-pass
  hipLaunchKernelGGL((gemm_mfma<96, 2, true>), dim3(12, 32), dim3(256), 0, stream,
                     Ahi, 3072, W1Thi, 3072, bp1,
                     h1hi, (float*)nullptr, 1536);

  // W2 split, then L2: 4096 x 896 x 1536, 1-pass
  hipLaunchKernelGGL((splitw_kernel<false>), dim3(48, 28), dim3(256), 0, stream,
                     W2, 1500, 800, W2Thi, 1536);
  hipLaunchKernelGGL((gemm_mfma<48, 2, true>), dim3(7, 32), dim3(256), 0, stream,
                     h1hi, 1536, W2Thi, 1536, bp2,
                     h2hi, (float*)nullptr, 896);

  // W3 split, then L3: 4096 x 128 x 896 (fp32 out), 64x128 tile, 1-pass
  hipLaunchKernelGGL((splitw_kernel<false>), dim3(28, 4), dim3(256), 0, stream,
                     W3, 800, 100, W3Thi, 896);
  hipLaunchKernelGGL((gemm_mfma<28, 1, false>), dim3(1, 64), dim3(128), 0, stream,
                     h2hi, 896, W3Thi, 896, bp3,
                     (u16*)nullptr, h3, 128);

  // fused mlp4 + concat + final head
  hipLaunchKernelGGL(tail_kernel, dim3(16), dim3(256), 0, stream,
                     h3, W4, b4, xg, Wc, bc, out);
}